// Round 11
// baseline (871.367 us; speedup 1.0000x reference)
//
#include <hip/hip_runtime.h>
#include <hip/hip_bf16.h>

#define NUM_NODES 100000
#define NUM_EDGES 100000
#define NNZ       1600000
#define D         64

#define BKT     128                          // targets per bucket
#define NBKT_E  ((NUM_EDGES + BKT - 1) / BKT)   // 782
#define NBKT_V  ((NUM_NODES + BKT - 1) / BKT)   // 782
#define NBKT_TOT (NBKT_E + NBKT_V)              // 1564
#define CAP     2816                         // padded words per bucket segment

#define TILE 8192                            // entries per bin tile
#define NT_SIDE ((NNZ + TILE - 1) / TILE)    // 196 tiles per side
#define NT_BIN  (2 * NT_SIDE)                // 392 bin blocks
#define GROWS   128                          // gemm rows per front block
#define NGEMM   ((NUM_NODES + GROWS - 1) / GROWS)   // 782
#define NFRONT  (3 * NT_SIDE * 2)            // 1176 = 392*3; roles 2:1 gemm:bin

// ---- bf16 helpers (RNE pack, shift unpack) --------------------------------
__device__ inline unsigned pack_bf16x2(float a, float b) {
  unsigned ua = __float_as_uint(a), ub = __float_as_uint(b);
  ua = (ua + 0x7fffu + ((ua >> 16) & 1u)) >> 16;
  ub = (ub + 0x7fffu + ((ub >> 16) & 1u)) >> 16;
  return ua | (ub << 16);
}
__device__ inline void unpack_acc(unsigned u, float& lo, float& hi) {
  lo = __uint_as_float(u << 16);
  hi = __uint_as_float(u & 0xffff0000u);
}

// ---------------------------------------------------------------------------
// Kernel 1: FRONT — fused independent gemm (Xp = bf16(X W^T + b)) and
// tile-binning. role: blockIdx%3==2 -> bin tile (392), else gemm (782+2 pad).
// Interleaved roles co-reside per CU: gemm's VALU work hides bin's
// latency-bound LDS/atomic phases. Cursors are RELATIVE (curb pre-zeroed).
// ---------------------------------------------------------------------------
__global__ __launch_bounds__(1024, 4) void front_k(
    const float* __restrict__ X, const float* __restrict__ W,
    const float* __restrict__ b, unsigned short* __restrict__ Xpb,
    const int* __restrict__ V, const int* __restrict__ E,
    int* __restrict__ curb, unsigned* __restrict__ pair) {
  __shared__ __align__(16) unsigned char smem[49664];
  const int t = threadIdx.x;
  const int blk = blockIdx.x;
  const int r3 = blk % 3;

  if (r3 != 2) {
    // ---------------- gemm role ----------------
    const int g = (blk / 3) * 2 + r3;
    if (g >= NGEMM) return;
    float (*Wl)[D + 1] = (float(*)[D + 1])smem;              // 16640 B
    float (*Xl)[D] = (float(*)[D])(smem + 16640);            // 32768 B
    for (int j = t; j < D * D; j += 1024) Wl[j >> 6][j & 63] = W[j];
    const int row0 = g * GROWS;
    // stage up to 128 rows of X (guard the tail block)
    for (int j = t; j < GROWS * (D / 4); j += 1024) {
      const int row = j >> 4;
      const int r = row0 + row;
      float4 x = make_float4(0.f, 0.f, 0.f, 0.f);
      if (r < NUM_NODES) x = ((const float4*)(X + (size_t)r * D))[j & 15];
      ((float4*)&Xl[0][0])[j] = x;
    }
    __syncthreads();

    const int c = t & 63;
    const int rq = t >> 6;           // 0..15
    float acc[8];
#pragma unroll
    for (int i = 0; i < 8; ++i) acc[i] = 0.f;
#pragma unroll
    for (int k = 0; k < D; ++k) {
      const float w = Wl[c][k];
#pragma unroll
      for (int i = 0; i < 8; ++i) acc[i] = fmaf(Xl[rq + i * 16][k], w, acc[i]);
    }
    const float bias = b[c];
#pragma unroll
    for (int i = 0; i < 8; ++i) {
      const int r = row0 + rq + i * 16;
      if (r < NUM_NODES) {
        const float v = acc[i] + bias;
        unsigned u = __float_as_uint(v);
        u = (u + 0x7fffu + ((u >> 16) & 1u)) >> 16;
        Xpb[(size_t)r * D + c] = (unsigned short)u;
      }
    }
  } else {
    // ---------------- bin role ----------------
    const int bt2 = blk / 3;                 // 0..391
    const int side = (bt2 >= NT_SIDE) ? 1 : 0;
    const int bt = bt2 - side * NT_SIDE;
    unsigned* stage = (unsigned*)smem;                       // 32768 B
    int* hist = (int*)(smem + 32768);                        // 3128 B
    int* gbase = (int*)(smem + 32768 + 3136);                // 3128 B
    int* lcur = (int*)(smem + 32768 + 6272);                 // 3128 B
    int* part = (int*)(smem + 32768 + 9408);                 // 4096 B
    const int j0 = bt * TILE;
    const int n = (NNZ - j0 < TILE) ? (NNZ - j0) : TILE;
    const int cbase = side ? NBKT_E : 0;

    for (int i = t; i < NBKT_E; i += 1024) hist[i] = 0;
    __syncthreads();

#pragma unroll
    for (int k = 0; k < TILE / 1024; ++k) {
      const int j = j0 + t + k * 1024;
      if (j - j0 < n) {
        const int key = side ? V[j] : E[j];
        atomicAdd(&hist[key >> 7], 1);
      }
    }
    __syncthreads();

    const int cb = (t < NBKT_E) ? hist[t] : 0;
    part[t] = cb;
    __syncthreads();
    for (int st = 1; st < 1024; st <<= 1) {
      const int x = part[t];
      const int add = (t >= st) ? part[t - st] : 0;
      __syncthreads();
      part[t] = x + add;
      __syncthreads();
    }
    if (t < NBKT_E) {
      const int o = part[t] - cb;   // exclusive local offset
      hist[t] = o;
      lcur[t] = o;
      gbase[t] = cb ? ((cbase + t) * CAP + atomicAdd(&curb[cbase + t], cb)) : 0;
    }
    __syncthreads();

#pragma unroll
    for (int k = 0; k < TILE / 1024; ++k) {
      const int j = j0 + t + k * 1024;
      if (j - j0 < n) {
        const int v = V[j], e = E[j];
        const int key = side ? v : e;
        const int src = side ? e : v;
        const int bb = key >> 7;
        const unsigned w = ((unsigned)src << 7) | (unsigned)(key & 127);
        const int pos = atomicAdd(&lcur[bb], 1);
        stage[pos] = w;
      }
    }
    __syncthreads();

    for (int sI = t; sI < n; sI += 1024) {
      int lo = 0, hi = NBKT_E - 1;
      while (lo < hi) {
        const int mid = (lo + hi + 1) >> 1;
        if (hist[mid] <= sI) lo = mid; else hi = mid - 1;
      }
      pair[gbase[lo] + (sI - hist[lo])] = stage[sI];
    }
  }
}

// ---------------------------------------------------------------------------
// Kernel 2: node degrees from node-side segments.
// ---------------------------------------------------------------------------
__global__ __launch_bounds__(256) void deg_node_k(
    const int* __restrict__ curb, const unsigned* __restrict__ pair,
    int* __restrict__ cnt_v) {
  __shared__ int rcnt[BKT];
  const int b = blockIdx.x, t = threadIdx.x;
  const int base = (NBKT_E + b) * CAP;
  int n = curb[NBKT_E + b];
  if (n > CAP) n = CAP;
  if (t < BKT) rcnt[t] = 0;
  __syncthreads();
  for (int j = t; j < n; j += 256) {
    atomicAdd(&rcnt[pair[base + j] & 127u], 1);
  }
  __syncthreads();
  const int v = b * BKT + t;
  if (t < BKT && v < NUM_NODES) cnt_v[v] = rcnt[t];
}

// ---------------------------------------------------------------------------
// Kernel 3: FUSED edge pass. One block = one edge bucket (128 edges).
// Degree sums (dsum) computed during the scatter phase — one cnt_v load per
// member + int LDS atomic (exact) — so the gather loop is pure row loads.
// ---------------------------------------------------------------------------
__global__ __launch_bounds__(512) void edge_fused_k(
    const int* __restrict__ curb, const unsigned* __restrict__ pair,
    const int* __restrict__ cnt_v, const uint4* __restrict__ Xpb,
    uint4* __restrict__ Yb) {
  __shared__ unsigned seg[CAP];
  __shared__ int sorted_[CAP];
  __shared__ int rcnt[BKT];
  __shared__ int sc[BKT];
  __shared__ int lcur[BKT];
  __shared__ int dsumi[BKT];
  const int b = blockIdx.x, t = threadIdx.x;
  const int base = b * CAP;
  int n = curb[b];
  if (n > CAP) n = CAP;
  const int e0 = b * BKT;
  const int nrows = (NUM_EDGES - e0 < BKT) ? (NUM_EDGES - e0) : BKT;

  if (t < BKT) { rcnt[t] = 0; dsumi[t] = 0; }
  __syncthreads();

  for (int j = t; j < n; j += 512) {
    const unsigned w = pair[base + j];
    seg[j] = w;
    atomicAdd(&rcnt[w & 127u], 1);
  }
  __syncthreads();

  if (t < BKT) sc[t] = rcnt[t];
  __syncthreads();
  for (int st = 1; st < BKT; st <<= 1) {
    int v = 0;
    if (t < BKT) v = (t >= st) ? sc[t - st] + sc[t] : sc[t];
    __syncthreads();
    if (t < BKT) sc[t] = v;
    __syncthreads();
  }
  if (t < BKT) lcur[t] = sc[t] - rcnt[t];
  __syncthreads();

  // row-sort member ids; accumulate integer degree sums per row
  for (int j = t; j < n; j += 512) {
    const unsigned w = seg[j];
    const int row = (int)(w & 127u);
    const int v = (int)(w >> 7);
    const int pos = atomicAdd(&lcur[row], 1);
    sorted_[pos] = v;
    atomicAdd(&dsumi[row], cnt_v[v]);
  }
  __syncthreads();

  const int q = t & 7;
#pragma unroll
  for (int rr = 0; rr < 2; ++rr) {
    const int row = (t >> 3) + rr * 64;
    const int ne = rcnt[row];
    const int mb = sc[row] - ne;
    const int me = sc[row];
    float acc[8];
#pragma unroll
    for (int i = 0; i < 8; ++i) acc[i] = 0.f;
    int m = mb;
    for (; m + 3 < me; m += 4) {
      const int v0 = sorted_[m], v1 = sorted_[m + 1];
      const int v2 = sorted_[m + 2], v3 = sorted_[m + 3];
      const uint4 w0 = Xpb[v0 * 8 + q];
      const uint4 w1 = Xpb[v1 * 8 + q];
      const uint4 w2 = Xpb[v2 * 8 + q];
      const uint4 w3 = Xpb[v3 * 8 + q];
      float lo, hi;
      unpack_acc(w0.x, lo, hi); acc[0] += lo; acc[1] += hi;
      unpack_acc(w0.y, lo, hi); acc[2] += lo; acc[3] += hi;
      unpack_acc(w0.z, lo, hi); acc[4] += lo; acc[5] += hi;
      unpack_acc(w0.w, lo, hi); acc[6] += lo; acc[7] += hi;
      unpack_acc(w1.x, lo, hi); acc[0] += lo; acc[1] += hi;
      unpack_acc(w1.y, lo, hi); acc[2] += lo; acc[3] += hi;
      unpack_acc(w1.z, lo, hi); acc[4] += lo; acc[5] += hi;
      unpack_acc(w1.w, lo, hi); acc[6] += lo; acc[7] += hi;
      unpack_acc(w2.x, lo, hi); acc[0] += lo; acc[1] += hi;
      unpack_acc(w2.y, lo, hi); acc[2] += lo; acc[3] += hi;
      unpack_acc(w2.z, lo, hi); acc[4] += lo; acc[5] += hi;
      unpack_acc(w2.w, lo, hi); acc[6] += lo; acc[7] += hi;
      unpack_acc(w3.x, lo, hi); acc[0] += lo; acc[1] += hi;
      unpack_acc(w3.y, lo, hi); acc[2] += lo; acc[3] += hi;
      unpack_acc(w3.z, lo, hi); acc[4] += lo; acc[5] += hi;
      unpack_acc(w3.w, lo, hi); acc[6] += lo; acc[7] += hi;
    }
    for (; m < me; ++m) {
      const uint4 w = Xpb[sorted_[m] * 8 + q];
      float lo, hi;
      unpack_acc(w.x, lo, hi); acc[0] += lo; acc[1] += hi;
      unpack_acc(w.y, lo, hi); acc[2] += lo; acc[3] += hi;
      unpack_acc(w.z, lo, hi); acc[4] += lo; acc[5] += hi;
      unpack_acc(w.w, lo, hi); acc[6] += lo; acc[7] += hi;
    }
    const float ce = (float)ne;
    const float De = (float)dsumi[row] / (ce + 1.f);
    const float inv = (De > 0.f) ? rsqrtf(fmaxf(De, 1e-30f)) : 1.f;
    const float s = inv / fmaxf(ce, 1.f);
    if (row < nrows) {
      uint4 o;
      o.x = pack_bf16x2(acc[0] * s, acc[1] * s);
      o.y = pack_bf16x2(acc[2] * s, acc[3] * s);
      o.z = pack_bf16x2(acc[4] * s, acc[5] * s);
      o.w = pack_bf16x2(acc[6] * s, acc[7] * s);
      Yb[(e0 + row) * 8 + q] = o;
    }
  }
}

// ---------------------------------------------------------------------------
// Kernel 4: FUSED node pass. One block = one node bucket (128 nodes).
// ---------------------------------------------------------------------------
__global__ __launch_bounds__(512) void node_fused_k(
    const int* __restrict__ curb, const unsigned* __restrict__ pair,
    const uint4* __restrict__ Yb, float* __restrict__ Out) {
  __shared__ unsigned seg[CAP];
  __shared__ int sorted_[CAP];
  __shared__ int rcnt[BKT];
  __shared__ int sc[BKT];
  __shared__ int lcur[BKT];
  const int b = blockIdx.x, t = threadIdx.x;
  const int base = (NBKT_E + b) * CAP;
  int n = curb[NBKT_E + b];
  if (n > CAP) n = CAP;
  const int v0r = b * BKT;
  const int nrows = (NUM_NODES - v0r < BKT) ? (NUM_NODES - v0r) : BKT;

  if (t < BKT) rcnt[t] = 0;
  __syncthreads();

  for (int j = t; j < n; j += 512) {
    const unsigned w = pair[base + j];
    seg[j] = w;
    atomicAdd(&rcnt[w & 127u], 1);
  }
  __syncthreads();

  if (t < BKT) sc[t] = rcnt[t];
  __syncthreads();
  for (int st = 1; st < BKT; st <<= 1) {
    int v = 0;
    if (t < BKT) v = (t >= st) ? sc[t - st] + sc[t] : sc[t];
    __syncthreads();
    if (t < BKT) sc[t] = v;
    __syncthreads();
  }
  if (t < BKT) lcur[t] = sc[t] - rcnt[t];
  __syncthreads();

  for (int j = t; j < n; j += 512) {
    const unsigned w = seg[j];
    const int pos = atomicAdd(&lcur[w & 127u], 1);
    sorted_[pos] = (int)(w >> 7);
  }
  __syncthreads();

  const int q = t & 7;
#pragma unroll
  for (int rr = 0; rr < 2; ++rr) {
    const int row = (t >> 3) + rr * 64;
    const int dv = rcnt[row];
    const int mb = sc[row] - dv;
    const int me = sc[row];
    float acc[8];
#pragma unroll
    for (int i = 0; i < 8; ++i) acc[i] = 0.f;
    int m = mb;
    for (; m + 3 < me; m += 4) {
      const int e0 = sorted_[m], e1 = sorted_[m + 1];
      const int e2 = sorted_[m + 2], e3 = sorted_[m + 3];
      const uint4 w0 = Yb[e0 * 8 + q];
      const uint4 w1 = Yb[e1 * 8 + q];
      const uint4 w2 = Yb[e2 * 8 + q];
      const uint4 w3 = Yb[e3 * 8 + q];
      float lo, hi;
      unpack_acc(w0.x, lo, hi); acc[0] += lo; acc[1] += hi;
      unpack_acc(w0.y, lo, hi); acc[2] += lo; acc[3] += hi;
      unpack_acc(w0.z, lo, hi); acc[4] += lo; acc[5] += hi;
      unpack_acc(w0.w, lo, hi); acc[6] += lo; acc[7] += hi;
      unpack_acc(w1.x, lo, hi); acc[0] += lo; acc[1] += hi;
      unpack_acc(w1.y, lo, hi); acc[2] += lo; acc[3] += hi;
      unpack_acc(w1.z, lo, hi); acc[4] += lo; acc[5] += hi;
      unpack_acc(w1.w, lo, hi); acc[6] += lo; acc[7] += hi;
      unpack_acc(w2.x, lo, hi); acc[0] += lo; acc[1] += hi;
      unpack_acc(w2.y, lo, hi); acc[2] += lo; acc[3] += hi;
      unpack_acc(w2.z, lo, hi); acc[4] += lo; acc[5] += hi;
      unpack_acc(w2.w, lo, hi); acc[6] += lo; acc[7] += hi;
      unpack_acc(w3.x, lo, hi); acc[0] += lo; acc[1] += hi;
      unpack_acc(w3.y, lo, hi); acc[2] += lo; acc[3] += hi;
      unpack_acc(w3.z, lo, hi); acc[4] += lo; acc[5] += hi;
      unpack_acc(w3.w, lo, hi); acc[6] += lo; acc[7] += hi;
    }
    for (; m < me; ++m) {
      const uint4 w = Yb[sorted_[m] * 8 + q];
      float lo, hi;
      unpack_acc(w.x, lo, hi); acc[0] += lo; acc[1] += hi;
      unpack_acc(w.y, lo, hi); acc[2] += lo; acc[3] += hi;
      unpack_acc(w.z, lo, hi); acc[4] += lo; acc[5] += hi;
      unpack_acc(w.w, lo, hi); acc[6] += lo; acc[7] += hi;
    }
    const float d = (float)dv;
    const float s = (d > 0.f) ? rsqrtf(d) : 0.f;
    if (row < nrows) {
      float4* O4 = (float4*)(Out + (size_t)(v0r + row) * D + q * 8);
      O4[0] = make_float4(acc[0] * s, acc[1] * s, acc[2] * s, acc[3] * s);
      O4[1] = make_float4(acc[4] * s, acc[5] * s, acc[6] * s, acc[7] * s);
    }
  }
}

extern "C" void kernel_launch(void* const* d_in, const int* in_sizes, int n_in,
                              void* d_out, int out_size, void* d_ws, size_t ws_size,
                              hipStream_t stream) {
  const float* X = (const float*)d_in[0];
  const int*   V = (const int*)d_in[1];
  const int*   E = (const int*)d_in[2];
  const float* W = (const float*)d_in[4];
  const float* b = (const float*)d_in[5];
  float* Out = (float*)d_out;

  // workspace layout (~44 MB)
  unsigned short* Xpb = (unsigned short*)d_ws;                 // 12.8 MB bf16
  unsigned short* Ybu = Xpb + (size_t)NUM_NODES * D;           // 12.8 MB bf16
  int*      curb   = (int*)(Ybu + (size_t)NUM_EDGES * D);      // 1564 (relative fills)
  int*      cnt_v  = curb + NBKT_TOT;                          // 400 KB
  unsigned* pair   = (unsigned*)(cnt_v + NUM_NODES);           // NBKT_TOT*CAP = 17.6 MB

  hipMemsetAsync(curb, 0, (size_t)NBKT_TOT * sizeof(int), stream);

  front_k<<<NFRONT, 1024, 0, stream>>>(X, W, b, Xpb, V, E, curb, pair);
  deg_node_k<<<NBKT_V, 256, 0, stream>>>(curb, pair, cnt_v);
  edge_fused_k<<<NBKT_E, 512, 0, stream>>>(
      curb, pair, cnt_v, (const uint4*)Xpb, (uint4*)Ybu);
  node_fused_k<<<NBKT_V, 512, 0, stream>>>(
      curb, pair, (const uint4*)Ybu, Out);
}

// Round 12
// 209.709 us; speedup vs baseline: 4.1551x; 4.1551x over previous
//
#include <hip/hip_runtime.h>
#include <hip/hip_bf16.h>

#define NUM_NODES 100000
#define NUM_EDGES 100000
#define NNZ       1600000
#define D         64

#define BKT     128                          // targets per bucket
#define NBKT_E  ((NUM_EDGES + BKT - 1) / BKT)   // 782
#define NBKT_V  ((NUM_NODES + BKT - 1) / BKT)   // 782
#define NBKT_TOT (NBKT_E + NBKT_V)              // 1564
#define CAP     2816                         // padded words per bucket segment

#define TILE 8192                            // entries per bin tile
#define NT_SIDE ((NNZ + TILE - 1) / TILE)    // 196 tiles per side

// ---- bf16 helpers (RNE pack, shift unpack) --------------------------------
__device__ inline unsigned pack_bf16x2(float a, float b) {
  unsigned ua = __float_as_uint(a), ub = __float_as_uint(b);
  ua = (ua + 0x7fffu + ((ua >> 16) & 1u)) >> 16;
  ub = (ub + 0x7fffu + ((ub >> 16) & 1u)) >> 16;
  return ua | (ub << 16);
}
__device__ inline void unpack_acc(unsigned u, float& lo, float& hi) {
  lo = __uint_as_float(u << 16);
  hi = __uint_as_float(u & 0xffff0000u);
}

// ---------------------------------------------------------------------------
// Kernel 1: Xp = bf16(X @ W^T + b)   (round-10 proven, standalone)
// ---------------------------------------------------------------------------
#define GEMM_ROWS 32
__global__ __launch_bounds__(256) void gemm_xw(
    const float* __restrict__ X, const float* __restrict__ W,
    const float* __restrict__ b, unsigned short* __restrict__ Xpb) {
  __shared__ float Wl[D][D + 1];
  __shared__ float Xl[GEMM_ROWS][D];
  const int t = threadIdx.x;

  for (int j = t; j < D * D; j += 256) Wl[j >> 6][j & 63] = W[j];
  const int row0 = blockIdx.x * GEMM_ROWS;
  const float4* X4 = (const float4*)(X + (size_t)row0 * D);
  float4* Xl4 = (float4*)&Xl[0][0];
  for (int j = t; j < GEMM_ROWS * (D / 4); j += 256) Xl4[j] = X4[j];
  __syncthreads();

  const int c = t & 63;
  const int rq = t >> 6;
  float acc[8];
#pragma unroll
  for (int i = 0; i < 8; ++i) acc[i] = 0.f;
#pragma unroll
  for (int k = 0; k < D; ++k) {
    const float w = Wl[c][k];
#pragma unroll
    for (int i = 0; i < 8; ++i) acc[i] = fmaf(Xl[rq + i * 4][k], w, acc[i]);
  }
  const float bias = b[c];
#pragma unroll
  for (int i = 0; i < 8; ++i) {
    const int r = row0 + rq + i * 4;
    const float v = acc[i] + bias;
    unsigned u = __float_as_uint(v);
    u = (u + 0x7fffu + ((u >> 16) & 1u)) >> 16;
    Xpb[(size_t)r * D + c] = (unsigned short)u;
  }
}

// ---------------------------------------------------------------------------
// Kernel 2: init bucket cursors to padded segment bases (b*CAP).
// ---------------------------------------------------------------------------
__global__ __launch_bounds__(256) void curb_init_k(int* __restrict__ curb) {
  const int b = blockIdx.x * blockDim.x + threadIdx.x;
  if (b < NBKT_TOT) curb[b] = b * CAP;
}

// ---------------------------------------------------------------------------
// Kernel 3: tile-local counting sort + bulk-reserved contiguous write-out.
// (round-8 proven, standalone — own register budget)
// ---------------------------------------------------------------------------
__global__ __launch_bounds__(1024, 4) void bin_tile_k(
    const int* __restrict__ V, const int* __restrict__ E,
    int* __restrict__ curb, unsigned* __restrict__ pair) {
  __shared__ unsigned stage[TILE];            // 32 KB
  __shared__ int hist[NBKT_E];                // counts -> exclusive offsets
  __shared__ int gbase[NBKT_E];
  __shared__ int lcur[NBKT_E];
  __shared__ int part[1024];

  const int t = threadIdx.x;
  const int side = (blockIdx.x >= NT_SIDE) ? 1 : 0;
  const int bt = blockIdx.x - side * NT_SIDE;
  const int j0 = bt * TILE;
  const int n = (NNZ - j0 < TILE) ? (NNZ - j0) : TILE;
  const int cbase = side ? NBKT_E : 0;

  for (int i = t; i < NBKT_E; i += 1024) hist[i] = 0;
  __syncthreads();

  // phase 1: tile histogram
#pragma unroll
  for (int k = 0; k < TILE / 1024; ++k) {
    const int j = j0 + t + k * 1024;
    if (j - j0 < n) {
      const int key = side ? V[j] : E[j];
      atomicAdd(&hist[key >> 7], 1);
    }
  }
  __syncthreads();

  // phase 2: scan + one global reservation per bucket
  const int cb = (t < NBKT_E) ? hist[t] : 0;
  part[t] = cb;
  __syncthreads();
  for (int st = 1; st < 1024; st <<= 1) {
    const int x = part[t];
    const int add = (t >= st) ? part[t - st] : 0;
    __syncthreads();
    part[t] = x + add;
    __syncthreads();
  }
  if (t < NBKT_E) {
    const int o = part[t] - cb;   // exclusive local offset
    hist[t] = o;
    lcur[t] = o;
    gbase[t] = cb ? atomicAdd(&curb[cbase + t], cb) : 0;
  }
  __syncthreads();

  // phase 3: local bucket-sort into stage
#pragma unroll
  for (int k = 0; k < TILE / 1024; ++k) {
    const int j = j0 + t + k * 1024;
    if (j - j0 < n) {
      const int v = V[j], e = E[j];
      const int key = side ? v : e;
      const int src = side ? e : v;
      const int b = key >> 7;
      const unsigned w = ((unsigned)src << 7) | (unsigned)(key & 127);
      const int pos = atomicAdd(&lcur[b], 1);
      stage[pos] = w;
    }
  }
  __syncthreads();

  // phase 4: dense write-out; bucket via binary search over hist offsets
  for (int sI = t; sI < n; sI += 1024) {
    int lo = 0, hi = NBKT_E - 1;
    while (lo < hi) {
      const int mid = (lo + hi + 1) >> 1;
      if (hist[mid] <= sI) lo = mid; else hi = mid - 1;
    }
    pair[gbase[lo] + (sI - hist[lo])] = stage[sI];
  }
}

// ---------------------------------------------------------------------------
// Kernel 4: node degrees from node-side segments.
// ---------------------------------------------------------------------------
__global__ __launch_bounds__(256) void deg_node_k(
    const int* __restrict__ curb, const unsigned* __restrict__ pair,
    int* __restrict__ cnt_v) {
  __shared__ int rcnt[BKT];
  const int b = blockIdx.x, t = threadIdx.x;
  const int base = (NBKT_E + b) * CAP;
  int n = curb[NBKT_E + b] - base;
  if (n > CAP) n = CAP;
  if (t < BKT) rcnt[t] = 0;
  __syncthreads();
  for (int j = t; j < n; j += 256) {
    atomicAdd(&rcnt[pair[base + j] & 127u], 1);
  }
  __syncthreads();
  const int v = b * BKT + t;
  if (t < BKT && v < NUM_NODES) cnt_v[v] = rcnt[t];
}

// ---------------------------------------------------------------------------
// Kernel 5: FUSED edge pass. One block = one edge bucket (128 edges).
// Degree sums hoisted into the scatter phase (int LDS atomic, exact) so the
// unrolled gather loop is pure uint4 row loads.
// ---------------------------------------------------------------------------
__global__ __launch_bounds__(512) void edge_fused_k(
    const int* __restrict__ curb, const unsigned* __restrict__ pair,
    const int* __restrict__ cnt_v, const uint4* __restrict__ Xpb,
    uint4* __restrict__ Yb) {
  __shared__ unsigned seg[CAP];
  __shared__ int sorted_[CAP];
  __shared__ int rcnt[BKT];
  __shared__ int sc[BKT];
  __shared__ int lcur[BKT];
  __shared__ int dsumi[BKT];
  const int b = blockIdx.x, t = threadIdx.x;
  const int base = b * CAP;
  int n = curb[b] - base;
  if (n > CAP) n = CAP;
  const int e0 = b * BKT;
  const int nrows = (NUM_EDGES - e0 < BKT) ? (NUM_EDGES - e0) : BKT;

  if (t < BKT) { rcnt[t] = 0; dsumi[t] = 0; }
  __syncthreads();

  for (int j = t; j < n; j += 512) {
    const unsigned w = pair[base + j];
    seg[j] = w;
    atomicAdd(&rcnt[w & 127u], 1);
  }
  __syncthreads();

  // exclusive scan of 128 row counts
  if (t < BKT) sc[t] = rcnt[t];
  __syncthreads();
  for (int st = 1; st < BKT; st <<= 1) {
    int v = 0;
    if (t < BKT) v = (t >= st) ? sc[t - st] + sc[t] : sc[t];
    __syncthreads();
    if (t < BKT) sc[t] = v;
    __syncthreads();
  }
  if (t < BKT) lcur[t] = sc[t] - rcnt[t];
  __syncthreads();

  // row-sort member ids; accumulate integer degree sums per row
  for (int j = t; j < n; j += 512) {
    const unsigned w = seg[j];
    const int row = (int)(w & 127u);
    const int v = (int)(w >> 7);
    const int pos = atomicAdd(&lcur[row], 1);
    sorted_[pos] = v;
    atomicAdd(&dsumi[row], cnt_v[v]);
  }
  __syncthreads();

  // gather: 8 lanes per row, 64 rows per pass, 2 passes; pure row loads
  const int q = t & 7;
#pragma unroll
  for (int rr = 0; rr < 2; ++rr) {
    const int row = (t >> 3) + rr * 64;
    const int ne = rcnt[row];
    const int mb = sc[row] - ne;
    const int me = sc[row];
    float acc[8];
#pragma unroll
    for (int i = 0; i < 8; ++i) acc[i] = 0.f;
    int m = mb;
    for (; m + 3 < me; m += 4) {
      const int v0 = sorted_[m], v1 = sorted_[m + 1];
      const int v2 = sorted_[m + 2], v3 = sorted_[m + 3];
      const uint4 w0 = Xpb[v0 * 8 + q];
      const uint4 w1 = Xpb[v1 * 8 + q];
      const uint4 w2 = Xpb[v2 * 8 + q];
      const uint4 w3 = Xpb[v3 * 8 + q];
      float lo, hi;
      unpack_acc(w0.x, lo, hi); acc[0] += lo; acc[1] += hi;
      unpack_acc(w0.y, lo, hi); acc[2] += lo; acc[3] += hi;
      unpack_acc(w0.z, lo, hi); acc[4] += lo; acc[5] += hi;
      unpack_acc(w0.w, lo, hi); acc[6] += lo; acc[7] += hi;
      unpack_acc(w1.x, lo, hi); acc[0] += lo; acc[1] += hi;
      unpack_acc(w1.y, lo, hi); acc[2] += lo; acc[3] += hi;
      unpack_acc(w1.z, lo, hi); acc[4] += lo; acc[5] += hi;
      unpack_acc(w1.w, lo, hi); acc[6] += lo; acc[7] += hi;
      unpack_acc(w2.x, lo, hi); acc[0] += lo; acc[1] += hi;
      unpack_acc(w2.y, lo, hi); acc[2] += lo; acc[3] += hi;
      unpack_acc(w2.z, lo, hi); acc[4] += lo; acc[5] += hi;
      unpack_acc(w2.w, lo, hi); acc[6] += lo; acc[7] += hi;
      unpack_acc(w3.x, lo, hi); acc[0] += lo; acc[1] += hi;
      unpack_acc(w3.y, lo, hi); acc[2] += lo; acc[3] += hi;
      unpack_acc(w3.z, lo, hi); acc[4] += lo; acc[5] += hi;
      unpack_acc(w3.w, lo, hi); acc[6] += lo; acc[7] += hi;
    }
    for (; m < me; ++m) {
      const uint4 w = Xpb[sorted_[m] * 8 + q];
      float lo, hi;
      unpack_acc(w.x, lo, hi); acc[0] += lo; acc[1] += hi;
      unpack_acc(w.y, lo, hi); acc[2] += lo; acc[3] += hi;
      unpack_acc(w.z, lo, hi); acc[4] += lo; acc[5] += hi;
      unpack_acc(w.w, lo, hi); acc[6] += lo; acc[7] += hi;
    }
    const float ce = (float)ne;
    const float De = (float)dsumi[row] / (ce + 1.f);
    const float inv = (De > 0.f) ? rsqrtf(fmaxf(De, 1e-30f)) : 1.f;
    const float s = inv / fmaxf(ce, 1.f);
    if (row < nrows) {
      uint4 o;
      o.x = pack_bf16x2(acc[0] * s, acc[1] * s);
      o.y = pack_bf16x2(acc[2] * s, acc[3] * s);
      o.z = pack_bf16x2(acc[4] * s, acc[5] * s);
      o.w = pack_bf16x2(acc[6] * s, acc[7] * s);
      Yb[(e0 + row) * 8 + q] = o;
    }
  }
}

// ---------------------------------------------------------------------------
// Kernel 6: FUSED node pass. One block = one node bucket (128 nodes).
// ---------------------------------------------------------------------------
__global__ __launch_bounds__(512) void node_fused_k(
    const int* __restrict__ curb, const unsigned* __restrict__ pair,
    const uint4* __restrict__ Yb, float* __restrict__ Out) {
  __shared__ unsigned seg[CAP];
  __shared__ int sorted_[CAP];
  __shared__ int rcnt[BKT];
  __shared__ int sc[BKT];
  __shared__ int lcur[BKT];
  const int b = blockIdx.x, t = threadIdx.x;
  const int base = (NBKT_E + b) * CAP;
  int n = curb[NBKT_E + b] - base;
  if (n > CAP) n = CAP;
  const int v0r = b * BKT;
  const int nrows = (NUM_NODES - v0r < BKT) ? (NUM_NODES - v0r) : BKT;

  if (t < BKT) rcnt[t] = 0;
  __syncthreads();

  for (int j = t; j < n; j += 512) {
    const unsigned w = pair[base + j];
    seg[j] = w;
    atomicAdd(&rcnt[w & 127u], 1);
  }
  __syncthreads();

  if (t < BKT) sc[t] = rcnt[t];
  __syncthreads();
  for (int st = 1; st < BKT; st <<= 1) {
    int v = 0;
    if (t < BKT) v = (t >= st) ? sc[t - st] + sc[t] : sc[t];
    __syncthreads();
    if (t < BKT) sc[t] = v;
    __syncthreads();
  }
  if (t < BKT) lcur[t] = sc[t] - rcnt[t];
  __syncthreads();

  for (int j = t; j < n; j += 512) {
    const unsigned w = seg[j];
    const int pos = atomicAdd(&lcur[w & 127u], 1);
    sorted_[pos] = (int)(w >> 7);
  }
  __syncthreads();

  const int q = t & 7;
#pragma unroll
  for (int rr = 0; rr < 2; ++rr) {
    const int row = (t >> 3) + rr * 64;
    const int dv = rcnt[row];
    const int mb = sc[row] - dv;
    const int me = sc[row];
    float acc[8];
#pragma unroll
    for (int i = 0; i < 8; ++i) acc[i] = 0.f;
    int m = mb;
    for (; m + 3 < me; m += 4) {
      const int e0 = sorted_[m], e1 = sorted_[m + 1];
      const int e2 = sorted_[m + 2], e3 = sorted_[m + 3];
      const uint4 w0 = Yb[e0 * 8 + q];
      const uint4 w1 = Yb[e1 * 8 + q];
      const uint4 w2 = Yb[e2 * 8 + q];
      const uint4 w3 = Yb[e3 * 8 + q];
      float lo, hi;
      unpack_acc(w0.x, lo, hi); acc[0] += lo; acc[1] += hi;
      unpack_acc(w0.y, lo, hi); acc[2] += lo; acc[3] += hi;
      unpack_acc(w0.z, lo, hi); acc[4] += lo; acc[5] += hi;
      unpack_acc(w0.w, lo, hi); acc[6] += lo; acc[7] += hi;
      unpack_acc(w1.x, lo, hi); acc[0] += lo; acc[1] += hi;
      unpack_acc(w1.y, lo, hi); acc[2] += lo; acc[3] += hi;
      unpack_acc(w1.z, lo, hi); acc[4] += lo; acc[5] += hi;
      unpack_acc(w1.w, lo, hi); acc[6] += lo; acc[7] += hi;
      unpack_acc(w2.x, lo, hi); acc[0] += lo; acc[1] += hi;
      unpack_acc(w2.y, lo, hi); acc[2] += lo; acc[3] += hi;
      unpack_acc(w2.z, lo, hi); acc[4] += lo; acc[5] += hi;
      unpack_acc(w2.w, lo, hi); acc[6] += lo; acc[7] += hi;
      unpack_acc(w3.x, lo, hi); acc[0] += lo; acc[1] += hi;
      unpack_acc(w3.y, lo, hi); acc[2] += lo; acc[3] += hi;
      unpack_acc(w3.z, lo, hi); acc[4] += lo; acc[5] += hi;
      unpack_acc(w3.w, lo, hi); acc[6] += lo; acc[7] += hi;
    }
    for (; m < me; ++m) {
      const uint4 w = Yb[sorted_[m] * 8 + q];
      float lo, hi;
      unpack_acc(w.x, lo, hi); acc[0] += lo; acc[1] += hi;
      unpack_acc(w.y, lo, hi); acc[2] += lo; acc[3] += hi;
      unpack_acc(w.z, lo, hi); acc[4] += lo; acc[5] += hi;
      unpack_acc(w.w, lo, hi); acc[6] += lo; acc[7] += hi;
    }
    const float d = (float)dv;
    const float s = (d > 0.f) ? rsqrtf(d) : 0.f;
    if (row < nrows) {
      float4* O4 = (float4*)(Out + (size_t)(v0r + row) * D + q * 8);
      O4[0] = make_float4(acc[0] * s, acc[1] * s, acc[2] * s, acc[3] * s);
      O4[1] = make_float4(acc[4] * s, acc[5] * s, acc[6] * s, acc[7] * s);
    }
  }
}

extern "C" void kernel_launch(void* const* d_in, const int* in_sizes, int n_in,
                              void* d_out, int out_size, void* d_ws, size_t ws_size,
                              hipStream_t stream) {
  const float* X = (const float*)d_in[0];
  const int*   V = (const int*)d_in[1];
  const int*   E = (const int*)d_in[2];
  const float* W = (const float*)d_in[4];
  const float* b = (const float*)d_in[5];
  float* Out = (float*)d_out;

  // workspace layout (~44 MB)
  unsigned short* Xpb = (unsigned short*)d_ws;                 // 12.8 MB bf16
  unsigned short* Ybu = Xpb + (size_t)NUM_NODES * D;           // 12.8 MB bf16
  int*      curb   = (int*)(Ybu + (size_t)NUM_EDGES * D);      // 1564
  int*      cnt_v  = curb + NBKT_TOT;                          // 400 KB
  unsigned* pair   = (unsigned*)(cnt_v + NUM_NODES);           // NBKT_TOT*CAP = 17.6 MB

  gemm_xw<<<NUM_NODES / GEMM_ROWS, 256, 0, stream>>>(X, W, b, Xpb);
  curb_init_k<<<(NBKT_TOT + 255) / 256, 256, 0, stream>>>(curb);
  bin_tile_k<<<2 * NT_SIDE, 1024, 0, stream>>>(V, E, curb, pair);
  deg_node_k<<<NBKT_V, 256, 0, stream>>>(curb, pair, cnt_v);
  edge_fused_k<<<NBKT_E, 512, 0, stream>>>(
      curb, pair, cnt_v, (const uint4*)Xpb, (uint4*)Ybu);
  node_fused_k<<<NBKT_V, 512, 0, stream>>>(
      curb, pair, (const uint4*)Ybu, Out);
}